// Round 1
// baseline (501.026 us; speedup 1.0000x reference)
//
#include <hip/hip_runtime.h>
#include <stdint.h>

typedef unsigned short ushort_t;
typedef unsigned int uint_t;

#define B_SZ 16
#define CIN 64
#define COUT 64
#define N_SZ 1024
#define L_SZ 12
#define CL 768            // COUT * L_SZ
#define ALPHA 0.2f

typedef __bf16 bf16x8 __attribute__((ext_vector_type(8)));
typedef float floatx4 __attribute__((ext_vector_type(4)));

__device__ __forceinline__ ushort_t f2bf(float x) {
    uint_t u = __float_as_uint(x);
    u += 0x7fffu + ((u >> 16) & 1u);
    return (ushort_t)(u >> 16);
}
__device__ __forceinline__ float bf2f(ushort_t h) {
    return __uint_as_float(((uint_t)h) << 16);
}

// ---------------------------------------------------------------------------
// K1: conv0 (1xKt=3, pad 1) + bias, fused f = sum_{co,l} x * w1.
// Writes Xt[b][m=co*12+l][n] bf16 (GEMM2 B-operand layout, n contiguous)
// and f[b][n] fp32.
// Block: 256 thr; grid (N/16, B). lane = co, wave w: nn = i*4 + w.
// ---------------------------------------------------------------------------
__global__ __launch_bounds__(256) void conv_f_kernel(
    const float* __restrict__ inp, const float* __restrict__ w0,
    const float* __restrict__ b0, const float* __restrict__ w1,
    ushort_t* __restrict__ Xt, float* __restrict__ fout)
{
    __shared__ float w0L[CIN * 192];  // [ci][co][kt]
    const int b = blockIdx.y;
    const int n0 = blockIdx.x * 16;
    const int t = threadIdx.x;

    for (int idx = t; idx < 12288; idx += 256) {
        int co = idx / 192, rem = idx - co * 192;
        int ci = rem / 3, kt = rem - ci * 3;
        w0L[ci * 192 + co * 3 + kt] = w0[idx];
    }
    __syncthreads();

    const int co = t & 63, wv = t >> 6;
    float w1r[12];
#pragma unroll
    for (int l = 0; l < 12; l++) w1r[l] = w1[co * 12 + l];
    const float b0v = b0[co];
    const float* inpB = inp + (size_t)b * CIN * N_SZ * L_SZ;

    float acc[4][12];
#pragma unroll
    for (int i = 0; i < 4; i++)
#pragma unroll
        for (int l = 0; l < 12; l++) acc[i][l] = 0.f;

    for (int ci = 0; ci < CIN; ci++) {
        const float* wrow = &w0L[ci * 192 + co * 3];
        const float wa = wrow[0], wb = wrow[1], wc = wrow[2];
        const float* ib = inpB + (size_t)ci * (N_SZ * L_SZ) + n0 * 12;
#pragma unroll
        for (int i = 0; i < 4; i++) {
            const int nn = i * 4 + wv;
            const float4 p0 = *(const float4*)(ib + nn * 12);
            const float4 p1 = *(const float4*)(ib + nn * 12 + 4);
            const float4 p2 = *(const float4*)(ib + nn * 12 + 8);
            const float p[12] = {p0.x, p0.y, p0.z, p0.w, p1.x, p1.y, p1.z, p1.w,
                                 p2.x, p2.y, p2.z, p2.w};
            acc[i][0] += p[0] * wb + p[1] * wc;
#pragma unroll
            for (int l = 1; l < 11; l++)
                acc[i][l] += p[l - 1] * wa + p[l] * wb + p[l + 1] * wc;
            acc[i][11] += p[10] * wa + p[11] * wb;
        }
    }

    ushort_t* XtB = Xt + (size_t)b * CL * N_SZ;
#pragma unroll
    for (int i = 0; i < 4; i++) {
        const int nn = i * 4 + wv;
        const int n = n0 + nn;
        float fp = 0.f;
#pragma unroll
        for (int l = 0; l < 12; l++) {
            const float x = acc[i][l] + b0v;
            fp += x * w1r[l];
            XtB[(size_t)(co * 12 + l) * N_SZ + n] = f2bf(x);
        }
#pragma unroll
        for (int o = 32; o; o >>= 1) fp += __shfl_xor(fp, o, 64);
        if (co == 0) fout[b * N_SZ + n] = fp;
    }
}

// ---------------------------------------------------------------------------
// K2: z = leaky(f_i + f_j) + adj; row softmax; store S bf16 (row-major).
// Block: 256 thr per row; grid (N, B).
// ---------------------------------------------------------------------------
__global__ __launch_bounds__(256) void softmax_kernel(
    const float* __restrict__ adj, const float* __restrict__ f,
    ushort_t* __restrict__ Sb)
{
    __shared__ float smx[4], sms[4];
    const int i = blockIdx.x, b = blockIdx.y, t = threadIdx.x;
    const int lane = t & 63, wv = t >> 6;

    const float* frow = f + b * N_SZ;
    const float fi = frow[i];
    const float4 fj = *(const float4*)(frow + 4 * t);
    const float4 av = *(const float4*)(adj + ((size_t)b * N_SZ + i) * N_SZ + 4 * t);

    float z[4];
    z[0] = fi + fj.x; z[1] = fi + fj.y; z[2] = fi + fj.z; z[3] = fi + fj.w;
#pragma unroll
    for (int k = 0; k < 4; k++) z[k] = (z[k] >= 0.f) ? z[k] : ALPHA * z[k];
    z[0] += av.x; z[1] += av.y; z[2] += av.z; z[3] += av.w;

    float mx = fmaxf(fmaxf(z[0], z[1]), fmaxf(z[2], z[3]));
#pragma unroll
    for (int o = 32; o; o >>= 1) mx = fmaxf(mx, __shfl_xor(mx, o, 64));
    if (lane == 0) smx[wv] = mx;
    __syncthreads();
    mx = fmaxf(fmaxf(smx[0], smx[1]), fmaxf(smx[2], smx[3]));

    float e[4], s = 0.f;
#pragma unroll
    for (int k = 0; k < 4; k++) { e[k] = __expf(z[k] - mx); s += e[k]; }
#pragma unroll
    for (int o = 32; o; o >>= 1) s += __shfl_xor(s, o, 64);
    if (lane == 0) sms[wv] = s;
    __syncthreads();
    s = sms[0] + sms[1] + sms[2] + sms[3];
    const float inv = 1.0f / s;

    const uint_t p0 = (uint_t)f2bf(e[0] * inv) | ((uint_t)f2bf(e[1] * inv) << 16);
    const uint_t p1 = (uint_t)f2bf(e[2] * inv) | ((uint_t)f2bf(e[3] * inv) << 16);
    uint2 pk; pk.x = p0; pk.y = p1;
    *(uint2*)&Sb[((size_t)b * N_SZ + i) * N_SZ + 4 * t] = pk;
}

// ---------------------------------------------------------------------------
// K3: attention output = S^T, bf16 -> fp32, LDS 64x64 tile transpose.
// grid (N/64, N/64, B): x = i-tile, y = j-tile.
// ---------------------------------------------------------------------------
__global__ __launch_bounds__(256) void att_transpose_kernel(
    const ushort_t* __restrict__ Sb, float* __restrict__ att)
{
    __shared__ float T[64][65];
    const int b = blockIdx.z;
    const int i0 = blockIdx.x * 64, j0 = blockIdx.y * 64;
    const int t = threadIdx.x;

#pragma unroll
    for (int ph = 0; ph < 2; ph++) {
        const int idx = ph * 256 + t;
        const int r = idx >> 3, c8 = (idx & 7) * 8;
        const uint4 v = *(const uint4*)(Sb + ((size_t)b * N_SZ + i0 + r) * N_SZ + j0 + c8);
        T[r][c8 + 0] = bf2f((ushort_t)(v.x & 0xffff));
        T[r][c8 + 1] = bf2f((ushort_t)(v.x >> 16));
        T[r][c8 + 2] = bf2f((ushort_t)(v.y & 0xffff));
        T[r][c8 + 3] = bf2f((ushort_t)(v.y >> 16));
        T[r][c8 + 4] = bf2f((ushort_t)(v.z & 0xffff));
        T[r][c8 + 5] = bf2f((ushort_t)(v.z >> 16));
        T[r][c8 + 6] = bf2f((ushort_t)(v.w & 0xffff));
        T[r][c8 + 7] = bf2f((ushort_t)(v.w >> 16));
    }
    __syncthreads();
#pragma unroll
    for (int ph = 0; ph < 4; ph++) {
        const int idx = ph * 256 + t;
        const int jr = idx >> 4, i4 = (idx & 15) * 4;
        float4 o;
        o.x = T[i4 + 0][jr]; o.y = T[i4 + 1][jr];
        o.z = T[i4 + 2][jr]; o.w = T[i4 + 3][jr];
        *(float4*)(att + ((size_t)b * N_SZ + j0 + jr) * N_SZ + i0 + i4) = o;
    }
}

// ---------------------------------------------------------------------------
// K4: per-batch GEMM  C[q,m] = sum_n S[q,n] * Xt[m,n], m=(co*12+l).
// 128x128 block tile, BK=32, 4 waves in 2x2, each wave 64x64 via 4x4
// mfma_f32_16x16x32_bf16. LDS layout: 16B units [kc][row] so both A and B
// fragment reads are single ds_read_b128. Epilogue scatters into NCHW out.
// grid (CL/128=6, N/128=8, B).
// ---------------------------------------------------------------------------
__global__ __launch_bounds__(256) void gemm2_kernel(
    const ushort_t* __restrict__ Sb, const ushort_t* __restrict__ Xt,
    float* __restrict__ out)
{
    __shared__ ushort_t As[512 * 8];
    __shared__ ushort_t Bs[512 * 8];
    const int b = blockIdx.z;
    const int m0 = blockIdx.x * 128, q0 = blockIdx.y * 128;
    const int t = threadIdx.x;
    const int lane = t & 63, wv = t >> 6;
    const int wq = wv >> 1, wm = wv & 1;
    const int kc = lane >> 4, rr = lane & 15;

    const ushort_t* Sbase = Sb + (size_t)b * N_SZ * N_SZ;
    const ushort_t* Xbase = Xt + (size_t)b * CL * N_SZ;

    floatx4 acc[4][4];
#pragma unroll
    for (int i = 0; i < 4; i++)
#pragma unroll
        for (int j = 0; j < 4; j++) acc[i][j] = (floatx4)0.f;

    for (int k0 = 0; k0 < N_SZ; k0 += 32) {
        __syncthreads();
#pragma unroll
        for (int c = 0; c < 2; c++) {
            const int u = c * 256 + t;
            const int r = u & 127, kcs = u >> 7;
            *(uint4*)&As[u * 8] =
                *(const uint4*)(Sbase + (size_t)(q0 + r) * N_SZ + k0 + kcs * 8);
            *(uint4*)&Bs[u * 8] =
                *(const uint4*)(Xbase + (size_t)(m0 + r) * N_SZ + k0 + kcs * 8);
        }
        __syncthreads();

        bf16x8 af[4], bf[4];
#pragma unroll
        for (int i = 0; i < 4; i++) {
            af[i] = *(const bf16x8*)&As[(kc * 128 + wq * 64 + i * 16 + rr) * 8];
            bf[i] = *(const bf16x8*)&Bs[(kc * 128 + wm * 64 + i * 16 + rr) * 8];
        }
#pragma unroll
        for (int i = 0; i < 4; i++)
#pragma unroll
            for (int j = 0; j < 4; j++)
                acc[i][j] = __builtin_amdgcn_mfma_f32_16x16x32_bf16(
                    af[i], bf[j], acc[i][j], 0, 0, 0);
    }

    // epilogue: C row = q (= kc*4 + reg within frag), col = m (= rr within frag)
#pragma unroll
    for (int j = 0; j < 4; j++) {
        const int m = m0 + wm * 64 + j * 16 + rr;
        const int co = m / 12, l = m - co * 12;
        float* ob = out + (size_t)(b * COUT + co) * (N_SZ * L_SZ) + l;
#pragma unroll
        for (int i = 0; i < 4; i++) {
            const int q = q0 + wq * 64 + i * 16 + kc * 4;
#pragma unroll
            for (int r2 = 0; r2 < 4; r2++)
                ob[(size_t)(q + r2) * 12] = acc[i][j][r2];
        }
    }
}

// ---------------------------------------------------------------------------
extern "C" void kernel_launch(void* const* d_in, const int* in_sizes, int n_in,
                              void* d_out, int out_size, void* d_ws, size_t ws_size,
                              hipStream_t stream)
{
    const float* inp = (const float*)d_in[0];
    const float* adj = (const float*)d_in[1];
    const float* w0  = (const float*)d_in[2];
    const float* b0  = (const float*)d_in[3];
    const float* w1  = (const float*)d_in[4];

    float* hprime = (float*)d_out;                       // 16*64*1024*12
    float* att    = hprime + (size_t)B_SZ * COUT * N_SZ * L_SZ;

    char* ws = (char*)d_ws;
    ushort_t* Xt = (ushort_t*)ws;                              // 25,165,824 B
    ushort_t* Sb = (ushort_t*)(ws + (size_t)25165824);         // 33,554,432 B
    float*    fw = (float*)(ws + (size_t)25165824 + 33554432); //     65,536 B

    conv_f_kernel<<<dim3(N_SZ / 16, B_SZ), 256, 0, stream>>>(inp, w0, b0, w1, Xt, fw);
    softmax_kernel<<<dim3(N_SZ, B_SZ), 256, 0, stream>>>(adj, fw, Sb);
    att_transpose_kernel<<<dim3(N_SZ / 64, N_SZ / 64, B_SZ), 256, 0, stream>>>(Sb, att);
    gemm2_kernel<<<dim3(CL / 128, N_SZ / 128, B_SZ), 256, 0, stream>>>(Sb, Xt, hprime);
}

// Round 2
// 349.756 us; speedup vs baseline: 1.4325x; 1.4325x over previous
//
#include <hip/hip_runtime.h>
#include <stdint.h>

typedef unsigned short ushort_t;
typedef unsigned int uint_t;

#define B_SZ 16
#define CIN 64
#define COUT 64
#define N_SZ 1024
#define L_SZ 12
#define CL 768            // COUT * L_SZ
#define ALPHA 0.2f

typedef __bf16 bf16x8 __attribute__((ext_vector_type(8)));
typedef float floatx4 __attribute__((ext_vector_type(4)));

__device__ __forceinline__ ushort_t f2bf(float x) {
    uint_t u = __float_as_uint(x);
    u += 0x7fffu + ((u >> 16) & 1u);
    return (ushort_t)(u >> 16);
}
__device__ __forceinline__ float bf2f(ushort_t h) {
    return __uint_as_float(((uint_t)h) << 16);
}

// ---------------------------------------------------------------------------
// K1: conv0 (1xKt=3, pad 1) + bias, fused partial f = sum_{co,l} x * w1.
// Lane = n (coalesced input, conflict-free LDS); weights broadcast from LDS.
// Grid (N/64=16, CoutGroups=4, B=16). Block 256 = 64 n  x  4 waves;
// wave ct handles co = cg*16 + ct*4 + {0..3}. Input staged in LDS in 4-ci
// chunks, row stride 15 (coprime to 32 -> conflict-free), zero-padded l.
// Writes Xt[b][m=co*12+l][n] bf16 and atomically accumulates f[b][n] fp32.
// ---------------------------------------------------------------------------
__global__ __launch_bounds__(256) void conv_f_kernel(
    const float* __restrict__ inp, const float* __restrict__ w0,
    const float* __restrict__ b0, const float* __restrict__ w1,
    ushort_t* __restrict__ Xt, float* __restrict__ fout)
{
    __shared__ float Din[4 * 64 * 15];   // [ci_c][n][slot 0..14], 15360 B
    __shared__ float w0L[64 * 16 * 3];   // [ci][co_l][kt], 12288 B
    __shared__ float w1L[16 * 12];       // [co_l][l]
    __shared__ float fred[256];

    const int n0 = blockIdx.x * 64;
    const int cb = blockIdx.y * 16;      // co base of this group
    const int b  = blockIdx.z;
    const int t  = threadIdx.x;
    const int n_l = t & 63, ct = t >> 6;

    // stage weights: w0 global layout [co][ci][kt], 192 floats per co
    for (int idx = t; idx < 3072; idx += 256) {
        const int co_l = idx / 192, rem = idx - co_l * 192;
        const int ci = rem / 3, kt = rem - ci * 3;
        w0L[ci * 48 + co_l * 3 + kt] = w0[cb * 192 + idx];
    }
    if (t < 192) w1L[t] = w1[cb * 12 + t];
    // zero the l-padding slots (0 and 13); staging only writes slots 1..12
    for (int q = t; q < 512; q += 256) {
        const int ci = q >> 7, r = q & 127;
        Din[ci * 960 + (r & 63) * 15 + ((r >> 6) ? 13 : 0)] = 0.f;
    }

    float acc[4][12];
#pragma unroll
    for (int c = 0; c < 4; c++)
#pragma unroll
        for (int l = 0; l < 12; l++) acc[c][l] = 0.f;

    const float* inpB = inp + (size_t)b * CIN * N_SZ * L_SZ + n0 * 12;

    for (int cc = 0; cc < 16; cc++) {
        __syncthreads();   // previous chunk's compute done (also covers init)
#pragma unroll
        for (int it = 0; it < 3; it++) {
            const int idx = it * 256 + t;           // 0..767
            const int ci_c = idx / 192, r = idx - ci_c * 192;
            const int n = r / 3, lg = r - n * 3;
            const float4 v = *(const float4*)(
                inpB + (size_t)(cc * 4 + ci_c) * (N_SZ * L_SZ) + n * 12 + lg * 4);
            float* d = &Din[ci_c * 960 + n * 15 + 1 + lg * 4];
            d[0] = v.x; d[1] = v.y; d[2] = v.z; d[3] = v.w;
        }
        __syncthreads();
#pragma unroll
        for (int cl = 0; cl < 4; cl++) {
            const int ci = cc * 4 + cl;
            const float* row = &Din[cl * 960 + n_l * 15];
            float p[14];
#pragma unroll
            for (int s = 0; s < 14; s++) p[s] = row[s];
            const float* wr = &w0L[ci * 48 + ct * 12];
#pragma unroll
            for (int c = 0; c < 4; c++) {
                const float wa = wr[c * 3], wb = wr[c * 3 + 1], wc = wr[c * 3 + 2];
#pragma unroll
                for (int l = 0; l < 12; l++)
                    acc[c][l] = fmaf(p[l], wa,
                                fmaf(p[l + 1], wb,
                                fmaf(p[l + 2], wc, acc[c][l])));
            }
        }
    }

    // epilogue: bias, bf16 store of Xt (coalesced over n), partial f
    const int n = n0 + n_l;
    ushort_t* XtB = Xt + (size_t)b * CL * N_SZ + n;
    float fp = 0.f;
#pragma unroll
    for (int c = 0; c < 4; c++) {
        const int co_l = ct * 4 + c;
        const float b0v = b0[cb + co_l];
#pragma unroll
        for (int l = 0; l < 12; l++) {
            const float x = acc[c][l] + b0v;
            fp += x * w1L[co_l * 12 + l];
            XtB[(size_t)((cb + co_l) * 12 + l) * N_SZ] = f2bf(x);
        }
    }
    fred[t] = fp;
    __syncthreads();
    if (t < 64) {
        const float s = fred[t] + fred[t + 64] + fred[t + 128] + fred[t + 192];
        atomicAdd(&fout[b * N_SZ + n0 + t], s);
    }
}

// ---------------------------------------------------------------------------
// K2: z = leaky(f_i + f_j) + adj; row softmax; store S bf16 (row-major).
// Block: 256 thr per row; grid (N, B).
// ---------------------------------------------------------------------------
__global__ __launch_bounds__(256) void softmax_kernel(
    const float* __restrict__ adj, const float* __restrict__ f,
    ushort_t* __restrict__ Sb)
{
    __shared__ float smx[4], sms[4];
    const int i = blockIdx.x, b = blockIdx.y, t = threadIdx.x;
    const int lane = t & 63, wv = t >> 6;

    const float* frow = f + b * N_SZ;
    const float fi = frow[i];
    const float4 fj = *(const float4*)(frow + 4 * t);
    const float4 av = *(const float4*)(adj + ((size_t)b * N_SZ + i) * N_SZ + 4 * t);

    float z[4];
    z[0] = fi + fj.x; z[1] = fi + fj.y; z[2] = fi + fj.z; z[3] = fi + fj.w;
#pragma unroll
    for (int k = 0; k < 4; k++) z[k] = (z[k] >= 0.f) ? z[k] : ALPHA * z[k];
    z[0] += av.x; z[1] += av.y; z[2] += av.z; z[3] += av.w;

    float mx = fmaxf(fmaxf(z[0], z[1]), fmaxf(z[2], z[3]));
#pragma unroll
    for (int o = 32; o; o >>= 1) mx = fmaxf(mx, __shfl_xor(mx, o, 64));
    if (lane == 0) smx[wv] = mx;
    __syncthreads();
    mx = fmaxf(fmaxf(smx[0], smx[1]), fmaxf(smx[2], smx[3]));

    float e[4], s = 0.f;
#pragma unroll
    for (int k = 0; k < 4; k++) { e[k] = __expf(z[k] - mx); s += e[k]; }
#pragma unroll
    for (int o = 32; o; o >>= 1) s += __shfl_xor(s, o, 64);
    if (lane == 0) sms[wv] = s;
    __syncthreads();
    s = sms[0] + sms[1] + sms[2] + sms[3];
    const float inv = 1.0f / s;

    const uint_t p0 = (uint_t)f2bf(e[0] * inv) | ((uint_t)f2bf(e[1] * inv) << 16);
    const uint_t p1 = (uint_t)f2bf(e[2] * inv) | ((uint_t)f2bf(e[3] * inv) << 16);
    uint2 pk; pk.x = p0; pk.y = p1;
    *(uint2*)&Sb[((size_t)b * N_SZ + i) * N_SZ + 4 * t] = pk;
}

// ---------------------------------------------------------------------------
// K3: attention output = S^T, bf16 -> fp32, LDS 64x64 tile transpose.
// grid (N/64, N/64, B): x = i-tile, y = j-tile.
// ---------------------------------------------------------------------------
__global__ __launch_bounds__(256) void att_transpose_kernel(
    const ushort_t* __restrict__ Sb, float* __restrict__ att)
{
    __shared__ float T[64][65];
    const int b = blockIdx.z;
    const int i0 = blockIdx.x * 64, j0 = blockIdx.y * 64;
    const int t = threadIdx.x;

#pragma unroll
    for (int ph = 0; ph < 2; ph++) {
        const int idx = ph * 256 + t;
        const int r = idx >> 3, c8 = (idx & 7) * 8;
        const uint4 v = *(const uint4*)(Sb + ((size_t)b * N_SZ + i0 + r) * N_SZ + j0 + c8);
        T[r][c8 + 0] = bf2f((ushort_t)(v.x & 0xffff));
        T[r][c8 + 1] = bf2f((ushort_t)(v.x >> 16));
        T[r][c8 + 2] = bf2f((ushort_t)(v.y & 0xffff));
        T[r][c8 + 3] = bf2f((ushort_t)(v.y >> 16));
        T[r][c8 + 4] = bf2f((ushort_t)(v.z & 0xffff));
        T[r][c8 + 5] = bf2f((ushort_t)(v.z >> 16));
        T[r][c8 + 6] = bf2f((ushort_t)(v.w & 0xffff));
        T[r][c8 + 7] = bf2f((ushort_t)(v.w >> 16));
    }
    __syncthreads();
#pragma unroll
    for (int ph = 0; ph < 4; ph++) {
        const int idx = ph * 256 + t;
        const int jr = idx >> 4, i4 = (idx & 15) * 4;
        float4 o;
        o.x = T[i4 + 0][jr]; o.y = T[i4 + 1][jr];
        o.z = T[i4 + 2][jr]; o.w = T[i4 + 3][jr];
        *(float4*)(att + ((size_t)b * N_SZ + j0 + jr) * N_SZ + i0 + i4) = o;
    }
}

// ---------------------------------------------------------------------------
// K4: per-batch GEMM  C[q,m] = sum_n S[q,n] * Xt[m,n], m=(co*12+l).
// 128x128 block tile, BK=32, 4 waves in 2x2, each wave 64x64 via 4x4
// mfma_f32_16x16x32_bf16. LDS layout: 16B units [kc][row] so both A and B
// fragment reads are single ds_read_b128. Epilogue scatters into NCHW out.
// grid (CL/128=6, N/128=8, B).
// ---------------------------------------------------------------------------
__global__ __launch_bounds__(256) void gemm2_kernel(
    const ushort_t* __restrict__ Sb, const ushort_t* __restrict__ Xt,
    float* __restrict__ out)
{
    __shared__ ushort_t As[512 * 8];
    __shared__ ushort_t Bs[512 * 8];
    const int b = blockIdx.z;
    const int m0 = blockIdx.x * 128, q0 = blockIdx.y * 128;
    const int t = threadIdx.x;
    const int lane = t & 63, wv = t >> 6;
    const int wq = wv >> 1, wm = wv & 1;
    const int kc = lane >> 4, rr = lane & 15;

    const ushort_t* Sbase = Sb + (size_t)b * N_SZ * N_SZ;
    const ushort_t* Xbase = Xt + (size_t)b * CL * N_SZ;

    floatx4 acc[4][4];
#pragma unroll
    for (int i = 0; i < 4; i++)
#pragma unroll
        for (int j = 0; j < 4; j++) acc[i][j] = (floatx4)0.f;

    for (int k0 = 0; k0 < N_SZ; k0 += 32) {
        __syncthreads();
#pragma unroll
        for (int c = 0; c < 2; c++) {
            const int u = c * 256 + t;
            const int r = u & 127, kcs = u >> 7;
            *(uint4*)&As[u * 8] =
                *(const uint4*)(Sbase + (size_t)(q0 + r) * N_SZ + k0 + kcs * 8);
            *(uint4*)&Bs[u * 8] =
                *(const uint4*)(Xbase + (size_t)(m0 + r) * N_SZ + k0 + kcs * 8);
        }
        __syncthreads();

        bf16x8 af[4], bf[4];
#pragma unroll
        for (int i = 0; i < 4; i++) {
            af[i] = *(const bf16x8*)&As[(kc * 128 + wq * 64 + i * 16 + rr) * 8];
            bf[i] = *(const bf16x8*)&Bs[(kc * 128 + wm * 64 + i * 16 + rr) * 8];
        }
#pragma unroll
        for (int i = 0; i < 4; i++)
#pragma unroll
            for (int j = 0; j < 4; j++)
                acc[i][j] = __builtin_amdgcn_mfma_f32_16x16x32_bf16(
                    af[i], bf[j], acc[i][j], 0, 0, 0);
    }

    // epilogue: C row = q (= kc*4 + reg within frag), col = m (= rr within frag)
#pragma unroll
    for (int j = 0; j < 4; j++) {
        const int m = m0 + wm * 64 + j * 16 + rr;
        const int co = m / 12, l = m - co * 12;
        float* ob = out + (size_t)(b * COUT + co) * (N_SZ * L_SZ) + l;
#pragma unroll
        for (int i = 0; i < 4; i++) {
            const int q = q0 + wq * 64 + i * 16 + kc * 4;
#pragma unroll
            for (int r2 = 0; r2 < 4; r2++)
                ob[(size_t)(q + r2) * 12] = acc[i][j][r2];
        }
    }
}

// ---------------------------------------------------------------------------
extern "C" void kernel_launch(void* const* d_in, const int* in_sizes, int n_in,
                              void* d_out, int out_size, void* d_ws, size_t ws_size,
                              hipStream_t stream)
{
    const float* inp = (const float*)d_in[0];
    const float* adj = (const float*)d_in[1];
    const float* w0  = (const float*)d_in[2];
    const float* b0  = (const float*)d_in[3];
    const float* w1  = (const float*)d_in[4];

    float* hprime = (float*)d_out;                       // 16*64*1024*12
    float* att    = hprime + (size_t)B_SZ * COUT * N_SZ * L_SZ;

    char* ws = (char*)d_ws;
    ushort_t* Xt = (ushort_t*)ws;                              // 25,165,824 B
    ushort_t* Sb = (ushort_t*)(ws + (size_t)25165824);         // 33,554,432 B
    float*    fw = (float*)(ws + (size_t)25165824 + 33554432); //     65,536 B

    hipMemsetAsync(fw, 0, B_SZ * N_SZ * sizeof(float), stream);
    conv_f_kernel<<<dim3(N_SZ / 64, 4, B_SZ), 256, 0, stream>>>(inp, w0, b0, w1, Xt, fw);
    softmax_kernel<<<dim3(N_SZ, B_SZ), 256, 0, stream>>>(adj, fw, Sb);
    att_transpose_kernel<<<dim3(N_SZ / 64, N_SZ / 64, B_SZ), 256, 0, stream>>>(Sb, att);
    gemm2_kernel<<<dim3(CL / 128, N_SZ / 128, B_SZ), 256, 0, stream>>>(Sb, Xt, hprime);
}

// Round 3
// 338.368 us; speedup vs baseline: 1.4807x; 1.0337x over previous
//
#include <hip/hip_runtime.h>
#include <stdint.h>

typedef unsigned short ushort_t;
typedef unsigned int uint_t;

#define B_SZ 16
#define CIN 64
#define COUT 64
#define N_SZ 1024
#define L_SZ 12
#define CL 768            // COUT * L_SZ
#define ALPHA 0.2f

typedef __bf16 bf16x8 __attribute__((ext_vector_type(8)));
typedef float floatx4 __attribute__((ext_vector_type(4)));

__device__ __forceinline__ ushort_t f2bf(float x) {
    uint_t u = __float_as_uint(x);
    u += 0x7fffu + ((u >> 16) & 1u);
    return (ushort_t)(u >> 16);
}
__device__ __forceinline__ float bf2f(ushort_t h) {
    return __uint_as_float(((uint_t)h) << 16);
}

// async global->LDS, 16B per lane; LDS dest must be wave-uniform base + lane*16
#define ASYNC16(ldsp, gp)                                                \
    __builtin_amdgcn_global_load_lds(                                    \
        (const __attribute__((address_space(1))) void*)(gp),             \
        (__attribute__((address_space(3))) void*)(ldsp), 16, 0, 0)

// ---------------------------------------------------------------------------
// K1: conv0 (1xKt=3, pad 1) + bias, fused partial f = sum_{co,l} x * w1.
// Lane = n. NO LDS input staging: each thread's input row is 48B contiguous,
// wave loads are 3KB coalesced; the 4 waves (co groups) re-read the same
// bytes L1-hot. 2-deep register pipeline over ci. Zero main-loop barriers.
// Grid (N/64=16, 4, B=16) = 1024 blocks = 4/CU. Writes Xt[b][m][n] bf16 and
// atomicAdds partial f[b][n].
// ---------------------------------------------------------------------------
__global__ __launch_bounds__(256, 4) void conv_f_kernel(
    const float* __restrict__ inp, const float* __restrict__ w0,
    const float* __restrict__ b0, const float* __restrict__ w1,
    ushort_t* __restrict__ Xt, float* __restrict__ fout)
{
    __shared__ float w0L[64 * 16 * 3];   // [ci][co_l][kt], 12288 B
    __shared__ float w1L[16 * 12];       // [co_l][l]
    __shared__ float fred[256];

    const int n0 = blockIdx.x * 64;
    const int cb = blockIdx.y * 16;      // co base of this group
    const int b  = blockIdx.z;
    const int t  = threadIdx.x;
    const int n_l = t & 63, ct = t >> 6;

    // stage weights: w0 global layout [co][ci][kt], 192 floats per co
    for (int idx = t; idx < 3072; idx += 256) {
        const int co_l = idx / 192, rem = idx - co_l * 192;
        const int ci = rem / 3, kt = rem - ci * 3;
        w0L[ci * 48 + co_l * 3 + kt] = w0[cb * 192 + idx];
    }
    if (t < 192) w1L[t] = w1[cb * 12 + t];
    __syncthreads();

    float acc[4][12];
#pragma unroll
    for (int c = 0; c < 4; c++)
#pragma unroll
        for (int l = 0; l < 12; l++) acc[c][l] = 0.f;

    const float* ib = inp + (size_t)b * CIN * N_SZ * L_SZ + (size_t)(n0 + n_l) * 12;

    float4 c0 = *(const float4*)(ib);
    float4 c1 = *(const float4*)(ib + 4);
    float4 c2 = *(const float4*)(ib + 8);

#pragma unroll 4
    for (int ci = 0; ci < 63; ci++) {
        const float* nb = ib + (size_t)(ci + 1) * (N_SZ * L_SZ);
        const float4 x0 = *(const float4*)(nb);
        const float4 x1 = *(const float4*)(nb + 4);
        const float4 x2 = *(const float4*)(nb + 8);
        const float p[12] = {c0.x, c0.y, c0.z, c0.w, c1.x, c1.y, c1.z, c1.w,
                             c2.x, c2.y, c2.z, c2.w};
        const float* wr = &w0L[ci * 48 + ct * 12];
#pragma unroll
        for (int c = 0; c < 4; c++) {
            const float wa = wr[c * 3], wb = wr[c * 3 + 1], wc = wr[c * 3 + 2];
            acc[c][0] = fmaf(p[0], wb, fmaf(p[1], wc, acc[c][0]));
#pragma unroll
            for (int l = 1; l < 11; l++)
                acc[c][l] = fmaf(p[l - 1], wa,
                            fmaf(p[l], wb, fmaf(p[l + 1], wc, acc[c][l])));
            acc[c][11] = fmaf(p[10], wa, fmaf(p[11], wb, acc[c][11]));
        }
        c0 = x0; c1 = x1; c2 = x2;
    }
    {   // ci = 63 epilogue iteration
        const float p[12] = {c0.x, c0.y, c0.z, c0.w, c1.x, c1.y, c1.z, c1.w,
                             c2.x, c2.y, c2.z, c2.w};
        const float* wr = &w0L[63 * 48 + ct * 12];
#pragma unroll
        for (int c = 0; c < 4; c++) {
            const float wa = wr[c * 3], wb = wr[c * 3 + 1], wc = wr[c * 3 + 2];
            acc[c][0] = fmaf(p[0], wb, fmaf(p[1], wc, acc[c][0]));
#pragma unroll
            for (int l = 1; l < 11; l++)
                acc[c][l] = fmaf(p[l - 1], wa,
                            fmaf(p[l], wb, fmaf(p[l + 1], wc, acc[c][l])));
            acc[c][11] = fmaf(p[10], wa, fmaf(p[11], wb, acc[c][11]));
        }
    }

    // epilogue: bias, bf16 store of Xt (coalesced over n), partial f
    const int n = n0 + n_l;
    ushort_t* XtB = Xt + (size_t)b * CL * N_SZ + n;
    float fp = 0.f;
#pragma unroll
    for (int c = 0; c < 4; c++) {
        const int co_l = ct * 4 + c;
        const float b0v = b0[cb + co_l];
#pragma unroll
        for (int l = 0; l < 12; l++) {
            const float x = acc[c][l] + b0v;
            fp += x * w1L[co_l * 12 + l];
            XtB[(size_t)((cb + co_l) * 12 + l) * N_SZ] = f2bf(x);
        }
    }
    fred[t] = fp;
    __syncthreads();
    if (t < 64) {
        const float s = fred[t] + fred[t + 64] + fred[t + 128] + fred[t + 192];
        atomicAdd(&fout[b * N_SZ + n0 + t], s);
    }
}

// ---------------------------------------------------------------------------
// K2: z = leaky(f_i + f_j) + adj; row softmax; store S bf16 (row-major).
// Block: 256 thr per row; grid (N, B).
// ---------------------------------------------------------------------------
__global__ __launch_bounds__(256) void softmax_kernel(
    const float* __restrict__ adj, const float* __restrict__ f,
    ushort_t* __restrict__ Sb)
{
    __shared__ float smx[4], sms[4];
    const int i = blockIdx.x, b = blockIdx.y, t = threadIdx.x;
    const int lane = t & 63, wv = t >> 6;

    const float* frow = f + b * N_SZ;
    const float fi = frow[i];
    const float4 fj = *(const float4*)(frow + 4 * t);
    const float4 av = *(const float4*)(adj + ((size_t)b * N_SZ + i) * N_SZ + 4 * t);

    float z[4];
    z[0] = fi + fj.x; z[1] = fi + fj.y; z[2] = fi + fj.z; z[3] = fi + fj.w;
#pragma unroll
    for (int k = 0; k < 4; k++) z[k] = (z[k] >= 0.f) ? z[k] : ALPHA * z[k];
    z[0] += av.x; z[1] += av.y; z[2] += av.z; z[3] += av.w;

    float mx = fmaxf(fmaxf(z[0], z[1]), fmaxf(z[2], z[3]));
#pragma unroll
    for (int o = 32; o; o >>= 1) mx = fmaxf(mx, __shfl_xor(mx, o, 64));
    if (lane == 0) smx[wv] = mx;
    __syncthreads();
    mx = fmaxf(fmaxf(smx[0], smx[1]), fmaxf(smx[2], smx[3]));

    float e[4], s = 0.f;
#pragma unroll
    for (int k = 0; k < 4; k++) { e[k] = __expf(z[k] - mx); s += e[k]; }
#pragma unroll
    for (int o = 32; o; o >>= 1) s += __shfl_xor(s, o, 64);
    if (lane == 0) sms[wv] = s;
    __syncthreads();
    s = sms[0] + sms[1] + sms[2] + sms[3];
    const float inv = 1.0f / s;

    const uint_t p0 = (uint_t)f2bf(e[0] * inv) | ((uint_t)f2bf(e[1] * inv) << 16);
    const uint_t p1 = (uint_t)f2bf(e[2] * inv) | ((uint_t)f2bf(e[3] * inv) << 16);
    uint2 pk; pk.x = p0; pk.y = p1;
    *(uint2*)&Sb[((size_t)b * N_SZ + i) * N_SZ + 4 * t] = pk;
}

// ---------------------------------------------------------------------------
// K3: attention output = S^T, bf16 -> fp32, LDS 64x64 tile transpose.
// grid (N/64, N/64, B): x = i-tile, y = j-tile.
// ---------------------------------------------------------------------------
__global__ __launch_bounds__(256) void att_transpose_kernel(
    const ushort_t* __restrict__ Sb, float* __restrict__ att)
{
    __shared__ float T[64][65];
    const int b = blockIdx.z;
    const int i0 = blockIdx.x * 64, j0 = blockIdx.y * 64;
    const int t = threadIdx.x;

#pragma unroll
    for (int ph = 0; ph < 2; ph++) {
        const int idx = ph * 256 + t;
        const int r = idx >> 3, c8 = (idx & 7) * 8;
        const uint4 v = *(const uint4*)(Sb + ((size_t)b * N_SZ + i0 + r) * N_SZ + j0 + c8);
        T[r][c8 + 0] = bf2f((ushort_t)(v.x & 0xffff));
        T[r][c8 + 1] = bf2f((ushort_t)(v.x >> 16));
        T[r][c8 + 2] = bf2f((ushort_t)(v.y & 0xffff));
        T[r][c8 + 3] = bf2f((ushort_t)(v.y >> 16));
        T[r][c8 + 4] = bf2f((ushort_t)(v.z & 0xffff));
        T[r][c8 + 5] = bf2f((ushort_t)(v.z >> 16));
        T[r][c8 + 6] = bf2f((ushort_t)(v.w & 0xffff));
        T[r][c8 + 7] = bf2f((ushort_t)(v.w >> 16));
    }
    __syncthreads();
#pragma unroll
    for (int ph = 0; ph < 4; ph++) {
        const int idx = ph * 256 + t;
        const int jr = idx >> 4, i4 = (idx & 15) * 4;
        float4 o;
        o.x = T[i4 + 0][jr]; o.y = T[i4 + 1][jr];
        o.z = T[i4 + 2][jr]; o.w = T[i4 + 3][jr];
        *(float4*)(att + ((size_t)b * N_SZ + j0 + jr) * N_SZ + i0 + i4) = o;
    }
}

// ---------------------------------------------------------------------------
// K4: per-batch GEMM  C[q,m] = sum_n S[q,n] * Xt[m,n], m=(co*12+l).
// 128x128 block tile, BK=32, 4 waves in 2x2, each wave 64x64 via 4x4
// mfma_f32_16x16x32_bf16. Staging via global_load_lds width=16 (m97 ladder
// step: no VGPR round-trip). LDS 16B-unit layout [kc][row] so both A and B
// fragment reads are single ds_read_b128. Epilogue scatters into NCHW out.
// grid (CL/128=6, N/128=8, B).
// ---------------------------------------------------------------------------
__global__ __launch_bounds__(256) void gemm2_kernel(
    const ushort_t* __restrict__ Sb, const ushort_t* __restrict__ Xt,
    float* __restrict__ out)
{
    __shared__ ushort_t As[512 * 8];
    __shared__ ushort_t Bs[512 * 8];
    const int b = blockIdx.z;
    const int m0 = blockIdx.x * 128, q0 = blockIdx.y * 128;
    const int t = threadIdx.x;
    const int lane = t & 63, wv = t >> 6;
    const int wq = wv >> 1, wm = wv & 1;
    const int kc = lane >> 4, rr = lane & 15;

    const ushort_t* Sbase = Sb + (size_t)b * N_SZ * N_SZ;
    const ushort_t* Xbase = Xt + (size_t)b * CL * N_SZ;

    floatx4 acc[4][4];
#pragma unroll
    for (int i = 0; i < 4; i++)
#pragma unroll
        for (int j = 0; j < 4; j++) acc[i][j] = (floatx4)0.f;

    for (int k0 = 0; k0 < N_SZ; k0 += 32) {
        __syncthreads();
#pragma unroll
        for (int c = 0; c < 2; c++) {
            const int u = c * 256 + t;
            const int r = u & 127, kcs = u >> 7;
            ASYNC16(&As[u * 8], Sbase + (size_t)(q0 + r) * N_SZ + k0 + kcs * 8);
            ASYNC16(&Bs[u * 8], Xbase + (size_t)(m0 + r) * N_SZ + k0 + kcs * 8);
        }
        __syncthreads();

        bf16x8 af[4], bfr[4];
#pragma unroll
        for (int i = 0; i < 4; i++) {
            af[i]  = *(const bf16x8*)&As[(kc * 128 + wq * 64 + i * 16 + rr) * 8];
            bfr[i] = *(const bf16x8*)&Bs[(kc * 128 + wm * 64 + i * 16 + rr) * 8];
        }
#pragma unroll
        for (int i = 0; i < 4; i++)
#pragma unroll
            for (int j = 0; j < 4; j++)
                acc[i][j] = __builtin_amdgcn_mfma_f32_16x16x32_bf16(
                    af[i], bfr[j], acc[i][j], 0, 0, 0);
    }

    // epilogue: C row = q (= kc*4 + reg within frag), col = m (= rr within frag)
#pragma unroll
    for (int j = 0; j < 4; j++) {
        const int m = m0 + wm * 64 + j * 16 + rr;
        const int co = m / 12, l = m - co * 12;
        float* ob = out + (size_t)(b * COUT + co) * (N_SZ * L_SZ) + l;
#pragma unroll
        for (int i = 0; i < 4; i++) {
            const int q = q0 + wq * 64 + i * 16 + kc * 4;
#pragma unroll
            for (int r2 = 0; r2 < 4; r2++)
                ob[(size_t)(q + r2) * 12] = acc[i][j][r2];
        }
    }
}

// ---------------------------------------------------------------------------
extern "C" void kernel_launch(void* const* d_in, const int* in_sizes, int n_in,
                              void* d_out, int out_size, void* d_ws, size_t ws_size,
                              hipStream_t stream)
{
    const float* inp = (const float*)d_in[0];
    const float* adj = (const float*)d_in[1];
    const float* w0  = (const float*)d_in[2];
    const float* b0  = (const float*)d_in[3];
    const float* w1  = (const float*)d_in[4];

    float* hprime = (float*)d_out;                       // 16*64*1024*12
    float* att    = hprime + (size_t)B_SZ * COUT * N_SZ * L_SZ;

    char* ws = (char*)d_ws;
    ushort_t* Xt = (ushort_t*)ws;                              // 25,165,824 B
    ushort_t* Sb = (ushort_t*)(ws + (size_t)25165824);         // 33,554,432 B
    float*    fw = (float*)(ws + (size_t)25165824 + 33554432); //     65,536 B

    hipMemsetAsync(fw, 0, B_SZ * N_SZ * sizeof(float), stream);
    conv_f_kernel<<<dim3(N_SZ / 64, 4, B_SZ), 256, 0, stream>>>(inp, w0, b0, w1, Xt, fw);
    softmax_kernel<<<dim3(N_SZ, B_SZ), 256, 0, stream>>>(adj, fw, Sb);
    att_transpose_kernel<<<dim3(N_SZ / 64, N_SZ / 64, B_SZ), 256, 0, stream>>>(Sb, att);
    gemm2_kernel<<<dim3(CL / 128, N_SZ / 128, B_SZ), 256, 0, stream>>>(Sb, Xt, hprime);
}